// Round 4
// baseline (173.237 us; speedup 1.0000x reference)
//
#include <hip/hip_runtime.h>
#include <hip/hip_cooperative_groups.h>
#include <stdint.h>

namespace cg = cooperative_groups;

// N=4, C=256, S=16, H*W=1024, 3 layers.
// W_eff[l,n] = (sum_k cw[l][:,k,:]) @ max(m[n],0) + exact sparse corrections for
// (n,k,b) columns whose slice-flag != 1 (rare; block-cooperative cold path).
// Single cooperative mega-kernel: phase A (prep + feats staging into persistent LDS)
// -> grid.sync -> phase B (wbase GEMM + corrections) -> grid.sync -> phase C (fused
// 3-layer chain). 256 blocks x 256 threads, 1 block/CU co-resident.
#define CC   256
#define NB   4
#define HWP  1024
#define EPSV 1e-5f

typedef __attribute__((ext_vector_type(8))) short bf16x8;
typedef __attribute__((ext_vector_type(4))) float f32x4;

__device__ __forceinline__ ushort f2bf(float f) {
    uint32_t u = __float_as_uint(f);
    uint32_t r = (u + 0x7FFFu + ((u >> 16) & 1u)) >> 16;   // RNE
    return (ushort)r;
}

__global__ __launch_bounds__(256) void mega_kernel(
    const float* __restrict__ adj,   const float* __restrict__ conv_w,
    const float* __restrict__ feats, const float* __restrict__ conv_b,
    const float* __restrict__ gamma, const float* __restrict__ beta,
    const float* __restrict__ mean,  const float* __restrict__ var,
    float* __restrict__ out,
    uint8_t* __restrict__ flags, ushort* __restrict__ cwS,
    ushort* __restrict__ mpT,    ushort* __restrict__ Ws) {
    cg::grid_group grid = cg::this_grid();
    const int t = threadIdx.x;
    const int bid = blockIdx.x;

    __shared__ float  Ms[64][68];        // phase A
    __shared__ ushort Al[64][40];        // phase B
    __shared__ ushort Bl[64][40];
    __shared__ int    s_badcnt;
    __shared__ int    s_bad[1024];
    __shared__ float  s_v[256];
    __shared__ float  s_corr[64];
    __shared__ ushort xl[2][16][264];    // phase C (staged in phase A; persists)

    const int wv = t >> 6, L = t & 63;
    const int l16 = L & 15, q = L >> 4;

    // ---------------- Phase A: prep + feats staging ----------------
    if (bid < 64) {
        const int n = bid >> 4;
        const int at = (bid >> 2) & 3, bt = bid & 3;
        const int a0 = at * 64, b0 = bt * 64;
        const float* m = adj + (size_t)n * CC * CC;
        {
            const int ar = t >> 2, bq = (t & 3) * 16;
            const float* src = m + (size_t)(a0 + ar) * CC + b0 + bq;
#pragma unroll
            for (int i = 0; i < 4; ++i)
                *(float4*)&Ms[ar][bq + i * 4] = *(const float4*)(src + i * 4);
        }
        __syncthreads();
        // transpose + relu -> bf16: mpT[n][b][a]
        {
            const int bl = t >> 2, ac = (t & 3) * 16;
            ushort* dst = mpT + ((size_t)n * CC + b0 + bl) * CC + a0 + ac;
#pragma unroll
            for (int a4 = 0; a4 < 4; ++a4) {
                ushort4 o;
                o.x = f2bf(fmaxf(Ms[ac + a4 * 4 + 0][bl], 0.f));
                o.y = f2bf(fmaxf(Ms[ac + a4 * 4 + 1][bl], 0.f));
                o.z = f2bf(fmaxf(Ms[ac + a4 * 4 + 2][bl], 0.f));
                o.w = f2bf(fmaxf(Ms[ac + a4 * 4 + 3][bl], 0.f));
                *(ushort4*)(dst + a4 * 4) = o;
            }
        }
        // flags[n][b][k]: 2 = all 16 rows of slice k positive at col b, 1 = any, 0 = none
        {
            const int kl = t >> 6, bl = t & 63;
            bool allp = true, anyp = false;
#pragma unroll
            for (int i = 0; i < 16; ++i) {
                bool p = Ms[kl * 16 + i][bl] > 0.0f;
                allp = allp && p;
                anyp = anyp || p;
            }
            const uint8_t f = allp ? (uint8_t)2 : (anyp ? (uint8_t)1 : (uint8_t)0);
            flags[(((size_t)n * CC) + b0 + bl) * 16 + at * 4 + kl] = f;
        }
    } else {
        // cwS[l][o][a] = bf16( sum_k conv_w[l][o][k*256+a] )
        const int idx = ((bid - 64) * 256 + t) * 4;   // over 3*256*256
        const float* src = conv_w + ((size_t)(idx >> 8)) * 4096 + (idx & 255);
        float4 s = {0.f, 0.f, 0.f, 0.f};
#pragma unroll
        for (int k = 0; k < 16; ++k) {
            float4 v = *(const float4*)(src + k * 256);
            s.x += v.x; s.y += v.y; s.z += v.z; s.w += v.w;
        }
        ushort4 ob = {f2bf(s.x), f2bf(s.y), f2bf(s.z), f2bf(s.w)};
        *(ushort4*)(cwS + idx) = ob;
    }
    // Stage this block's phase-C x0 panel: thread t = channel, 16 p-values.
    {
        const int n = bid >> 6, p0 = (bid & 63) * 16;
        const float* src = feats + ((size_t)n * CC + t) * HWP + p0;
        float v[16];
#pragma unroll
        for (int i = 0; i < 4; ++i)
            *(float4*)&v[i * 4] = *(const float4*)(src + i * 4);
#pragma unroll
        for (int i = 0; i < 16; ++i)
            xl[0][i][t] = f2bf(v[i]);
    }
    grid.sync();

    // ---------------- Phase B: Ws = bf16(sc * (cwS @ mpT^T - corr)) ----------------
    if (bid < 192) {
        const int tile = bid & 15, ln = bid >> 4;
        const int l = ln >> 2, n = ln & 3;
        const int trow = (tile >> 2) * 64, tcol = (tile & 3) * 64;
        const ushort* A = cwS + (size_t)l * 65536;     // [o][a], a contig
        const ushort* B = mpT + (size_t)n * 65536;     // [b][a], a contig
        const int wr = (wv >> 1) * 32, wc = (wv & 1) * 32;
        const int r0 = t >> 2, kq0 = (t & 3) * 8;
        f32x4 acc[2][2];
#pragma unroll
        for (int i = 0; i < 2; ++i)
#pragma unroll
            for (int j = 0; j < 2; ++j)
                acc[i][j] = (f32x4){0.f, 0.f, 0.f, 0.f};

        if (t == 0) s_badcnt = 0;

        for (int kt = 0; kt < 8; ++kt) {
            const int kk = kt * 32;
            int4 av = *(const int4*)(A + (size_t)(trow + r0) * CC + kk + kq0);
            int4 bv = *(const int4*)(B + (size_t)(tcol + r0) * CC + kk + kq0);
            __syncthreads();
            *(int4*)&Al[r0][kq0] = av;
            *(int4*)&Bl[r0][kq0] = bv;
            __syncthreads();
            bf16x8 af[2], bfr[2];
#pragma unroll
            for (int i = 0; i < 2; ++i)
                af[i] = *(const bf16x8*)&Al[wr + i * 16 + l16][q * 8];
#pragma unroll
            for (int j = 0; j < 2; ++j)
                bfr[j] = *(const bf16x8*)&Bl[wc + j * 16 + l16][q * 8];
#pragma unroll
            for (int i = 0; i < 2; ++i)
#pragma unroll
                for (int j = 0; j < 2; ++j)
                    acc[i][j] = __builtin_amdgcn_mfma_f32_16x16x32_bf16(af[i], bfr[j], acc[i][j], 0, 0, 0);
        }

        // scan this block's 64 columns for flag!=1 entries (common case: none)
        if (t < 64) {
            const uint8_t* fb = flags + (((size_t)n * CC) + tcol + t) * 16;
            const uint4 fv = *(const uint4*)fb;
            if ((fv.x != 0x01010101u) || (fv.y != 0x01010101u) ||
                (fv.z != 0x01010101u) || (fv.w != 0x01010101u)) {
                for (int k = 0; k < 16; ++k) {
                    const int f = fb[k];
                    if (f != 1) {
                        int pos = atomicAdd(&s_badcnt, 1);
                        s_bad[pos] = (t << 8) | (k << 2) | f;
                    }
                }
            }
        }
        __syncthreads();
        const int nbad = s_badcnt;
        for (int e = 0; e < nbad; ++e) {            // block-uniform cold path
            const int enc = s_bad[e];
            const int bl = enc >> 8, k = (enc >> 2) & 15, f = enc & 3;
            const int b = tcol + bl;
            {
                const float mv = adj[(size_t)n * 65536 + (size_t)t * CC + b];
                s_v[t] = (f == 0) ? fmaxf(mv, 0.f) : fmaxf(-mv, 0.f);
            }
            __syncthreads();
            {
                const float* cw = conv_w + (size_t)l * 1048576 +
                                  (size_t)(trow + (t >> 2)) * 4096 + k * 256 + (t & 3) * 64;
                const float* vv = s_v + (t & 3) * 64;
                float s = 0.f;
#pragma unroll 16
                for (int a = 0; a < 64; ++a) s += cw[a] * vv[a];
                s += __shfl_xor(s, 1);
                s += __shfl_xor(s, 2);
                if ((t & 3) == 0) s_corr[t >> 2] = s;
            }
            __syncthreads();
#pragma unroll
            for (int j = 0; j < 2; ++j) {
                if (wc + j * 16 + l16 == bl) {
#pragma unroll
                    for (int i = 0; i < 2; ++i)
#pragma unroll
                        for (int r = 0; r < 4; ++r)
                            acc[i][j][r] -= s_corr[wr + i * 16 + q * 4 + r];
                }
            }
            __syncthreads();
        }

        ushort* W = Ws + (size_t)ln * 65536;
#pragma unroll
        for (int i = 0; i < 2; ++i)
#pragma unroll
            for (int j = 0; j < 2; ++j) {
                const int ob = trow + wr + i * 16 + q * 4;   // D row = quad*4 + reg
                const int b  = tcol + wc + j * 16 + l16;     // D col = lane&15
#pragma unroll
                for (int r = 0; r < 4; ++r) {
                    const int o = ob + r;
                    const float sc = gamma[l * CC + o] * rsqrtf(var[l * CC + o] + EPSV);
                    W[(size_t)o * CC + b] = f2bf(acc[i][j][r] * sc);
                }
            }
    }
    grid.sync();

    // ---------------- Phase C: fused 3-layer chain ----------------
    {
        const int n = bid >> 6, p0 = (bid & 63) * 16;
        int cur = 0;
        for (int l = 0; l < 3; ++l) {
            const ushort* Bw = Ws + (size_t)(l * 4 + n) * 65536;   // [o][b], b contig
            f32x4 acc[4];
#pragma unroll
            for (int jj = 0; jj < 4; ++jj) acc[jj] = (f32x4){0.f, 0.f, 0.f, 0.f};

#pragma unroll
            for (int kt = 0; kt < 8; ++kt) {
                const int kk = kt * 32;
                bf16x8 af = *(const bf16x8*)&xl[cur][l16][kk + q * 8];
#pragma unroll
                for (int jj = 0; jj < 4; ++jj) {
                    const int o = (wv * 4 + jj) * 16 + l16;
                    bf16x8 bv = *(const bf16x8*)(Bw + (size_t)o * CC + kk + q * 8);
                    acc[jj] = __builtin_amdgcn_mfma_f32_16x16x32_bf16(af, bv, acc[jj], 0, 0, 0);
                }
            }

            float* outn = out + (size_t)(l * 4 + n) * CC * HWP;
#pragma unroll
            for (int jj = 0; jj < 4; ++jj) {
                const int o = (wv * 4 + jj) * 16 + l16;
                const float sc = gamma[l * CC + o] * rsqrtf(var[l * CC + o] + EPSV);
                const float b2 = sc * (conv_b[l * CC + o] - mean[l * CC + o]) + beta[l * CC + o];
                const float v0 = fmaxf(acc[jj][0] + b2, 0.f);
                const float v1 = fmaxf(acc[jj][1] + b2, 0.f);
                const float v2 = fmaxf(acc[jj][2] + b2, 0.f);
                const float v3 = fmaxf(acc[jj][3] + b2, 0.f);
                *(float4*)(outn + (size_t)o * HWP + p0 + q * 4) = (float4){v0, v1, v2, v3};
                if (l < 2) {
                    xl[cur ^ 1][q * 4 + 0][o] = f2bf(v0);
                    xl[cur ^ 1][q * 4 + 1][o] = f2bf(v1);
                    xl[cur ^ 1][q * 4 + 2][o] = f2bf(v2);
                    xl[cur ^ 1][q * 4 + 3][o] = f2bf(v3);
                }
            }
            __syncthreads();
            cur ^= 1;
        }
    }
}

// ---------------------------------------------------------------------------
extern "C" void kernel_launch(void* const* d_in, const int* in_sizes, int n_in,
                              void* d_out, int out_size, void* d_ws, size_t ws_size,
                              hipStream_t stream) {
    const float* adj    = (const float*)d_in[1];
    const float* conv_w = (const float*)d_in[2];
    const float* feats  = (const float*)d_in[0];
    const float* conv_b = (const float*)d_in[3];
    const float* gamma  = (const float*)d_in[4];
    const float* beta   = (const float*)d_in[5];
    const float* mean   = (const float*)d_in[6];
    const float* var    = (const float*)d_in[7];
    float* out = (float*)d_out;

    // ws layout (bytes):
    //   [0, 16384)            flags uint8 [4][256][16]
    //   [16384, +393216)      cwS bf16 [3][256][256]
    //   [409600, +524288)     mpT bf16 [4][256][256]
    //   [933888, +1572864)    Ws  bf16 [12][256][256]
    char* ws = (char*)d_ws;
    uint8_t* flags = (uint8_t*)ws;
    ushort*  cwS   = (ushort*)(ws + 16384);
    ushort*  mpT   = (ushort*)(ws + 409600);
    ushort*  Wsb   = (ushort*)(ws + 933888);

    void* args[] = {(void*)&adj, (void*)&conv_w, (void*)&feats, (void*)&conv_b,
                    (void*)&gamma, (void*)&beta, (void*)&mean, (void*)&var,
                    (void*)&out, (void*)&flags, (void*)&cwS, (void*)&mpT, (void*)&Wsb};
    hipLaunchCooperativeKernel((void*)mega_kernel, dim3(256), dim3(256), args, 0, stream);
}

// Round 5
// 109.302 us; speedup vs baseline: 1.5849x; 1.5849x over previous
//
#include <hip/hip_runtime.h>
#include <stdint.h>

// N=4, C=256, S=16, H*W=1024, 3 layers.
// W_eff[l,n] = (sum_k cw[l][:,k,:]) @ max(m[n],0) + exact sparse corrections for
// (n,k,b) columns whose slice-flag != 1 (rare; block-cooperative cold path).
// Pipeline: prep -> wbase_mfma (2-stage BK=128 staging) -> fused_layers (512 thr).
// R4 lesson: cooperative grid.sync costs ~30us/sync on 8-XCD MI355X — never again.
#define CC   256
#define NB   4
#define HWP  1024
#define EPSV 1e-5f

typedef __attribute__((ext_vector_type(8))) short bf16x8;
typedef __attribute__((ext_vector_type(4))) float f32x4;

__device__ __forceinline__ ushort f2bf(float f) {
    uint32_t u = __float_as_uint(f);
    uint32_t r = (u + 0x7FFFu + ((u >> 16) & 1u)) >> 16;   // RNE
    return (ushort)r;
}

// ---------------------------------------------------------------------------
// Blocks 0..63:   per n, 64x64 tile: mpT[n][b][a] = bf16(max(m[a,b],0)) (K=a contig)
//                 + flags[n][b][k] byte: 2 = all 16 rows of slice k positive at col b,
//                   1 = any, 0 = none.
// Blocks 64..255: cwS[l][o][a] = bf16( sum_k conv_w[l][o][k*256+a] ) (fp32 accumulate).
__global__ __launch_bounds__(256) void prep_kernel(const float* __restrict__ adj,
                                                   const float* __restrict__ conv_w,
                                                   ushort* __restrict__ mpT,
                                                   uint8_t* __restrict__ flags,
                                                   ushort* __restrict__ cwS) {
    const int t = threadIdx.x;
    if (blockIdx.x < 64) {
        const int bb = blockIdx.x;
        const int n = bb >> 4;
        const int at = (bb >> 2) & 3, bt = bb & 3;
        const int a0 = at * 64, b0 = bt * 64;
        const float* m = adj + (size_t)n * CC * CC;
        __shared__ float Ms[64][68];
        {
            const int ar = t >> 2, bq = (t & 3) * 16;
            const float* src = m + (size_t)(a0 + ar) * CC + b0 + bq;
#pragma unroll
            for (int i = 0; i < 4; ++i)
                *(float4*)&Ms[ar][bq + i * 4] = *(const float4*)(src + i * 4);
        }
        __syncthreads();
        // transpose + relu -> bf16
        {
            const int bl = t >> 2, ac = (t & 3) * 16;
            ushort* dst = mpT + ((size_t)n * CC + b0 + bl) * CC + a0 + ac;
#pragma unroll
            for (int a4 = 0; a4 < 4; ++a4) {
                ushort4 o;
                o.x = f2bf(fmaxf(Ms[ac + a4 * 4 + 0][bl], 0.f));
                o.y = f2bf(fmaxf(Ms[ac + a4 * 4 + 1][bl], 0.f));
                o.z = f2bf(fmaxf(Ms[ac + a4 * 4 + 2][bl], 0.f));
                o.w = f2bf(fmaxf(Ms[ac + a4 * 4 + 3][bl], 0.f));
                *(ushort4*)(dst + a4 * 4) = o;
            }
        }
        // flags: slice k = at*4 + kl, col b0+bl
        {
            const int kl = t >> 6, bl = t & 63;
            bool allp = true, anyp = false;
#pragma unroll
            for (int i = 0; i < 16; ++i) {
                bool p = Ms[kl * 16 + i][bl] > 0.0f;
                allp = allp && p;
                anyp = anyp || p;
            }
            const uint8_t f = allp ? (uint8_t)2 : (anyp ? (uint8_t)1 : (uint8_t)0);
            flags[(((size_t)n * CC) + b0 + bl) * 16 + at * 4 + kl] = f;
        }
    } else {
        const int idx = ((blockIdx.x - 64) * 256 + t) * 4;   // over 3*256*256
        const float* src = conv_w + ((size_t)(idx >> 8)) * 4096 + (idx & 255);
        float4 s = {0.f, 0.f, 0.f, 0.f};
#pragma unroll
        for (int k = 0; k < 16; ++k) {
            float4 v = *(const float4*)(src + k * 256);
            s.x += v.x; s.y += v.y; s.z += v.z; s.w += v.w;
        }
        ushort4 ob = {f2bf(s.x), f2bf(s.y), f2bf(s.z), f2bf(s.w)};
        *(ushort4*)(cwS + idx) = ob;
    }
}

// ---------------------------------------------------------------------------
// Ws[l,n][o][b] = bf16( sc_o * ( cwS[l] @ mpT[n]^T  - corrections ) )
// Batched 256x256x256 bf16 MFMA GEMM; 64x64 tiles, 4 waves x (2x2) frags; grid (16,12).
// Two-stage BK=128 staging: global latency paid ~once; stage-2 loads issued before
// stage-1 MFMAs so they overlap. 3 barriers total (vs 16 in the per-BK32 loop).
__global__ __launch_bounds__(256) void wbase_mfma(const ushort* __restrict__ cwS,
                                                  const ushort* __restrict__ mpT,
                                                  const uint8_t* __restrict__ flags,
                                                  const float* __restrict__ adj,
                                                  const float* __restrict__ conv_w,
                                                  const float* __restrict__ gamma,
                                                  const float* __restrict__ var,
                                                  ushort* __restrict__ Ws) {
    const int tile = blockIdx.x;
    const int ln = blockIdx.y;
    const int l = ln >> 2, n = ln & 3;
    const int trow = (tile >> 2) * 64, tcol = (tile & 3) * 64;
    const ushort* A = cwS + (size_t)l * 65536;     // [o][a], a contig
    const ushort* B = mpT + (size_t)n * 65536;     // [b][a], a contig
    __shared__ ushort Al[64][130];   // odd word-stride: conflict-free frag reads
    __shared__ ushort Bl[64][130];
    __shared__ int   s_badcnt;
    __shared__ int   s_bad[1024];   // (b_local<<8)|(k<<2)|f
    __shared__ float s_v[256];
    __shared__ float s_corr[64];
    const int t = threadIdx.x;
    const int wv = t >> 6, L = t & 63;
    const int wr = (wv >> 1) * 32, wc = (wv & 1) * 32;
    const int l16 = L & 15, q = L >> 4;
    const int lr = t >> 2, lc0 = (t & 3) * 32;     // load row / col base (shorts)
    f32x4 acc[2][2];
#pragma unroll
    for (int i = 0; i < 2; ++i)
#pragma unroll
        for (int j = 0; j < 2; ++j)
            acc[i][j] = (f32x4){0.f, 0.f, 0.f, 0.f};

    if (t == 0) s_badcnt = 0;

    const ushort* Arow = A + (size_t)(trow + lr) * CC + lc0;
    const ushort* Brow = B + (size_t)(tcol + lr) * CC + lc0;
    int4 a1[4], b1[4], a2[4], b2[4];
#pragma unroll
    for (int j = 0; j < 4; ++j) a1[j] = *(const int4*)(Arow + j * 8);
#pragma unroll
    for (int j = 0; j < 4; ++j) b1[j] = *(const int4*)(Brow + j * 8);
#pragma unroll
    for (int j = 0; j < 4; ++j) {
        *(int4*)&Al[lr][lc0 + j * 8] = a1[j];
        *(int4*)&Bl[lr][lc0 + j * 8] = b1[j];
    }
    __syncthreads();
    // stage-2 loads in flight while stage-1 MFMAs run
#pragma unroll
    for (int j = 0; j < 4; ++j) a2[j] = *(const int4*)(Arow + 128 + j * 8);
#pragma unroll
    for (int j = 0; j < 4; ++j) b2[j] = *(const int4*)(Brow + 128 + j * 8);
#pragma unroll
    for (int ktl = 0; ktl < 4; ++ktl) {
        bf16x8 af[2], bfr[2];
#pragma unroll
        for (int i = 0; i < 2; ++i)
            af[i] = *(const bf16x8*)&Al[wr + i * 16 + l16][ktl * 32 + q * 8];
#pragma unroll
        for (int j = 0; j < 2; ++j)
            bfr[j] = *(const bf16x8*)&Bl[wc + j * 16 + l16][ktl * 32 + q * 8];
#pragma unroll
        for (int i = 0; i < 2; ++i)
#pragma unroll
            for (int j = 0; j < 2; ++j)
                acc[i][j] = __builtin_amdgcn_mfma_f32_16x16x32_bf16(af[i], bfr[j], acc[i][j], 0, 0, 0);
    }
    __syncthreads();
#pragma unroll
    for (int j = 0; j < 4; ++j) {
        *(int4*)&Al[lr][lc0 + j * 8] = a2[j];
        *(int4*)&Bl[lr][lc0 + j * 8] = b2[j];
    }
    __syncthreads();
#pragma unroll
    for (int ktl = 0; ktl < 4; ++ktl) {
        bf16x8 af[2], bfr[2];
#pragma unroll
        for (int i = 0; i < 2; ++i)
            af[i] = *(const bf16x8*)&Al[wr + i * 16 + l16][ktl * 32 + q * 8];
#pragma unroll
        for (int j = 0; j < 2; ++j)
            bfr[j] = *(const bf16x8*)&Bl[wc + j * 16 + l16][ktl * 32 + q * 8];
#pragma unroll
        for (int i = 0; i < 2; ++i)
#pragma unroll
            for (int j = 0; j < 2; ++j)
                acc[i][j] = __builtin_amdgcn_mfma_f32_16x16x32_bf16(af[i], bfr[j], acc[i][j], 0, 0, 0);
    }

    // --- scan this block's 64 columns for flag!=1 entries (common case: none) ---
    if (t < 64) {
        const uint8_t* fb = flags + (((size_t)n * CC) + tcol + t) * 16;
        const uint4 fv = *(const uint4*)fb;
        if ((fv.x != 0x01010101u) || (fv.y != 0x01010101u) ||
            (fv.z != 0x01010101u) || (fv.w != 0x01010101u)) {
            for (int k = 0; k < 16; ++k) {
                const int f = fb[k];
                if (f != 1) {
                    int pos = atomicAdd(&s_badcnt, 1);
                    s_bad[pos] = (t << 8) | (k << 2) | f;
                }
            }
        }
    }
    __syncthreads();
    const int nbad = s_badcnt;
    for (int e = 0; e < nbad; ++e) {            // block-uniform cold path
        const int enc = s_bad[e];
        const int bl = enc >> 8, k = (enc >> 2) & 15, f = enc & 3;
        const int b = tcol + bl;
        {
            const float mv = adj[(size_t)n * 65536 + (size_t)t * CC + b];
            s_v[t] = (f == 0) ? fmaxf(mv, 0.f) : fmaxf(-mv, 0.f);
        }
        __syncthreads();
        {
            const float* cw = conv_w + (size_t)l * 1048576 +
                              (size_t)(trow + (t >> 2)) * 4096 + k * 256 + (t & 3) * 64;
            const float* vv = s_v + (t & 3) * 64;
            float s = 0.f;
#pragma unroll 16
            for (int a = 0; a < 64; ++a) s += cw[a] * vv[a];
            s += __shfl_xor(s, 1);
            s += __shfl_xor(s, 2);
            if ((t & 3) == 0) s_corr[t >> 2] = s;
        }
        __syncthreads();
#pragma unroll
        for (int j = 0; j < 2; ++j) {
            if (wc + j * 16 + l16 == bl) {
#pragma unroll
                for (int i = 0; i < 2; ++i)
#pragma unroll
                    for (int r = 0; r < 4; ++r)
                        acc[i][j][r] -= s_corr[wr + i * 16 + q * 4 + r];
            }
        }
        __syncthreads();
    }

    ushort* W = Ws + (size_t)ln * 65536;
#pragma unroll
    for (int i = 0; i < 2; ++i)
#pragma unroll
        for (int j = 0; j < 2; ++j) {
            const int ob = trow + wr + i * 16 + q * 4;       // D row = quad*4 + reg
            const int b  = tcol + wc + j * 16 + l16;         // D col = lane&15
#pragma unroll
            for (int r = 0; r < 4; ++r) {
                const int o = ob + r;
                const float sc = gamma[l * CC + o] * rsqrtf(var[l * CC + o] + EPSV);
                W[(size_t)o * CC + b] = f2bf(acc[i][j][r] * sc);
            }
        }
}

// ---------------------------------------------------------------------------
// Fused 3-layer chain. Block owns 16 p-rows x all 256 channels of one n.
// 512 threads (8 waves, 2 waves/SIMD) for 2x latency hiding on scattered W reads.
// Wave wv owns o-frags wv*2..wv*2+1. x panel in LDS ping-pong; W streamed from L2.
__global__ __launch_bounds__(512) void fused_layers(const float* __restrict__ feats,
                                                    const ushort* __restrict__ Ws,
                                                    const float* __restrict__ conv_b,
                                                    const float* __restrict__ gamma,
                                                    const float* __restrict__ beta,
                                                    const float* __restrict__ mean,
                                                    const float* __restrict__ var,
                                                    float* __restrict__ out) {
    const int n = blockIdx.y;
    const int p0 = blockIdx.x * 16;
    __shared__ ushort xl[2][16][264];   // +8 shorts pad
    const int t = threadIdx.x;
    const int wv = t >> 6, L = t & 63;
    const int l16 = L & 15, q = L >> 4;

    // Load + transpose x0: thread t = (channel c = t>>1, half = t&1), 8 p-values.
    {
        const int c = t >> 1, h = t & 1;
        const float* src = feats + ((size_t)n * CC + c) * HWP + p0 + h * 8;
        float v[8];
#pragma unroll
        for (int i = 0; i < 2; ++i)
            *(float4*)&v[i * 4] = *(const float4*)(src + i * 4);
#pragma unroll
        for (int i = 0; i < 8; ++i)
            xl[0][h * 8 + i][c] = f2bf(v[i]);
    }
    __syncthreads();

    int cur = 0;
    for (int l = 0; l < 3; ++l) {
        const ushort* Bw = Ws + (size_t)(l * 4 + n) * 65536;   // [o][b], b contig
        f32x4 acc[2];
#pragma unroll
        for (int jj = 0; jj < 2; ++jj) acc[jj] = (f32x4){0.f, 0.f, 0.f, 0.f};

#pragma unroll
        for (int kt = 0; kt < 8; ++kt) {
            const int kk = kt * 32;
            bf16x8 af = *(const bf16x8*)&xl[cur][l16][kk + q * 8];
#pragma unroll
            for (int jj = 0; jj < 2; ++jj) {
                const int o = (wv * 2 + jj) * 16 + l16;
                bf16x8 bv = *(const bf16x8*)(Bw + (size_t)o * CC + kk + q * 8);
                acc[jj] = __builtin_amdgcn_mfma_f32_16x16x32_bf16(af, bv, acc[jj], 0, 0, 0);
            }
        }

        float* outn = out + (size_t)(l * 4 + n) * CC * HWP;
#pragma unroll
        for (int jj = 0; jj < 2; ++jj) {
            const int o = (wv * 2 + jj) * 16 + l16;
            const float sc = gamma[l * CC + o] * rsqrtf(var[l * CC + o] + EPSV);
            const float b2 = sc * (conv_b[l * CC + o] - mean[l * CC + o]) + beta[l * CC + o];
            const float v0 = fmaxf(acc[jj][0] + b2, 0.f);
            const float v1 = fmaxf(acc[jj][1] + b2, 0.f);
            const float v2 = fmaxf(acc[jj][2] + b2, 0.f);
            const float v3 = fmaxf(acc[jj][3] + b2, 0.f);
            *(float4*)(outn + (size_t)o * HWP + p0 + q * 4) = (float4){v0, v1, v2, v3};
            if (l < 2) {
                xl[cur ^ 1][q * 4 + 0][o] = f2bf(v0);
                xl[cur ^ 1][q * 4 + 1][o] = f2bf(v1);
                xl[cur ^ 1][q * 4 + 2][o] = f2bf(v2);
                xl[cur ^ 1][q * 4 + 3][o] = f2bf(v3);
            }
        }
        __syncthreads();
        cur ^= 1;
    }
}

// ---------------------------------------------------------------------------
extern "C" void kernel_launch(void* const* d_in, const int* in_sizes, int n_in,
                              void* d_out, int out_size, void* d_ws, size_t ws_size,
                              hipStream_t stream) {
    const float* feats  = (const float*)d_in[0];
    const float* adj    = (const float*)d_in[1];
    const float* conv_w = (const float*)d_in[2];
    const float* conv_b = (const float*)d_in[3];
    const float* gamma  = (const float*)d_in[4];
    const float* beta   = (const float*)d_in[5];
    const float* mean   = (const float*)d_in[6];
    const float* var    = (const float*)d_in[7];
    float* out = (float*)d_out;

    // ws layout (bytes):
    //   [0, 16384)            flags uint8 [4][256][16]
    //   [16384, +393216)      cwS bf16 [3][256][256]
    //   [409600, +524288)     mpT bf16 [4][256][256]
    //   [933888, +1572864)    Ws  bf16 [12][256][256]
    char* ws = (char*)d_ws;
    uint8_t* flags = (uint8_t*)ws;
    ushort*  cwS   = (ushort*)(ws + 16384);
    ushort*  mpT   = (ushort*)(ws + 409600);
    ushort*  Wsb   = (ushort*)(ws + 933888);

    prep_kernel<<<256, 256, 0, stream>>>(adj, conv_w, mpT, flags, cwS);
    wbase_mfma<<<dim3(16, 12), 256, 0, stream>>>(cwS, mpT, flags, adj, conv_w, gamma, var, Wsb);
    fused_layers<<<dim3(64, NB), 512, 0, stream>>>(feats, Wsb, conv_b, gamma, beta, mean, var, out);
}

// Round 6
// 105.591 us; speedup vs baseline: 1.6407x; 1.0352x over previous
//
#include <hip/hip_runtime.h>
#include <stdint.h>

// N=4, C=256, S=16, H*W=1024, 3 layers.
// W_eff[l,n] = (sum_k cw[l][:,k,:]) @ max(m[n],0) + exact sparse corrections for
// (n,k,b) columns whose slice-flag != 1 (rare; block-cooperative cold path).
// Pipeline: prep -> wbase_mfma (LDS-free, direct-L2 fragment GEMM) -> fused_layers.
// R4 lesson: cooperative grid.sync costs ~30us/sync on 8-XCD MI355X — never again.
#define CC   256
#define NB   4
#define HWP  1024
#define EPSV 1e-5f

typedef __attribute__((ext_vector_type(8))) short bf16x8;
typedef __attribute__((ext_vector_type(4))) float f32x4;

__device__ __forceinline__ ushort f2bf(float f) {
    uint32_t u = __float_as_uint(f);
    uint32_t r = (u + 0x7FFFu + ((u >> 16) & 1u)) >> 16;   // RNE
    return (ushort)r;
}

// ---------------------------------------------------------------------------
// Blocks 0..63:   per n, 64x64 tile: mpT[n][b][a] = bf16(max(m[a,b],0)) (K=a contig)
//                 + flags[n][b][k] byte: 2 = all 16 rows of slice k positive at col b,
//                   1 = any, 0 = none.
// Blocks 64..255: cwS[l][o][a] = bf16( sum_k conv_w[l][o][k*256+a] ) (fp32 accumulate).
__global__ __launch_bounds__(256) void prep_kernel(const float* __restrict__ adj,
                                                   const float* __restrict__ conv_w,
                                                   ushort* __restrict__ mpT,
                                                   uint8_t* __restrict__ flags,
                                                   ushort* __restrict__ cwS) {
    const int t = threadIdx.x;
    if (blockIdx.x < 64) {
        const int bb = blockIdx.x;
        const int n = bb >> 4;
        const int at = (bb >> 2) & 3, bt = bb & 3;
        const int a0 = at * 64, b0 = bt * 64;
        const float* m = adj + (size_t)n * CC * CC;
        __shared__ float Ms[64][68];
        {
            const int ar = t >> 2, bq = (t & 3) * 16;
            const float* src = m + (size_t)(a0 + ar) * CC + b0 + bq;
#pragma unroll
            for (int i = 0; i < 4; ++i)
                *(float4*)&Ms[ar][bq + i * 4] = *(const float4*)(src + i * 4);
        }
        __syncthreads();
        // transpose + relu -> bf16
        {
            const int bl = t >> 2, ac = (t & 3) * 16;
            ushort* dst = mpT + ((size_t)n * CC + b0 + bl) * CC + a0 + ac;
#pragma unroll
            for (int a4 = 0; a4 < 4; ++a4) {
                ushort4 o;
                o.x = f2bf(fmaxf(Ms[ac + a4 * 4 + 0][bl], 0.f));
                o.y = f2bf(fmaxf(Ms[ac + a4 * 4 + 1][bl], 0.f));
                o.z = f2bf(fmaxf(Ms[ac + a4 * 4 + 2][bl], 0.f));
                o.w = f2bf(fmaxf(Ms[ac + a4 * 4 + 3][bl], 0.f));
                *(ushort4*)(dst + a4 * 4) = o;
            }
        }
        // flags: slice k = at*4 + kl, col b0+bl
        {
            const int kl = t >> 6, bl = t & 63;
            bool allp = true, anyp = false;
#pragma unroll
            for (int i = 0; i < 16; ++i) {
                bool p = Ms[kl * 16 + i][bl] > 0.0f;
                allp = allp && p;
                anyp = anyp || p;
            }
            const uint8_t f = allp ? (uint8_t)2 : (anyp ? (uint8_t)1 : (uint8_t)0);
            flags[(((size_t)n * CC) + b0 + bl) * 16 + at * 4 + kl] = f;
        }
    } else {
        const int idx = ((blockIdx.x - 64) * 256 + t) * 4;   // over 3*256*256
        const float* src = conv_w + ((size_t)(idx >> 8)) * 4096 + (idx & 255);
        float4 s = {0.f, 0.f, 0.f, 0.f};
#pragma unroll
        for (int k = 0; k < 16; ++k) {
            float4 v = *(const float4*)(src + k * 256);
            s.x += v.x; s.y += v.y; s.z += v.z; s.w += v.w;
        }
        ushort4 ob = {f2bf(s.x), f2bf(s.y), f2bf(s.z), f2bf(s.w)};
        *(ushort4*)(cwS + idx) = ob;
    }
}

// ---------------------------------------------------------------------------
// Ws[l,n][o][b] = bf16( sc_o * ( cwS[l] @ mpT[n]^T  - corrections ) )
// Batched 256x256x256 bf16 MFMA GEMM; 64x64 tiles, 4 waves x (2x2) frags; grid (16,12).
// LDS-FREE: A/B fragments are loaded straight from L2 (operands are K-contiguous and
// 16B-aligned per lane) — no staging, no barriers in the GEMM. 2x intra-block read
// redundancy on a 25 MB L2 stream is ~free; removing 3 barriers + LDS round-trip isn't.
__global__ __launch_bounds__(256) void wbase_mfma(const ushort* __restrict__ cwS,
                                                  const ushort* __restrict__ mpT,
                                                  const uint8_t* __restrict__ flags,
                                                  const float* __restrict__ adj,
                                                  const float* __restrict__ conv_w,
                                                  const float* __restrict__ gamma,
                                                  const float* __restrict__ var,
                                                  ushort* __restrict__ Ws) {
    const int tile = blockIdx.x;
    const int ln = blockIdx.y;
    const int l = ln >> 2, n = ln & 3;
    const int trow = (tile >> 2) * 64, tcol = (tile & 3) * 64;
    const ushort* A = cwS + (size_t)l * 65536;     // [o][a], a contig
    const ushort* B = mpT + (size_t)n * 65536;     // [b][a], a contig
    __shared__ int   s_badcnt;
    __shared__ int   s_bad[1024];   // (b_local<<8)|(k<<2)|f
    __shared__ float s_v[256];
    __shared__ float s_corr[64];
    const int t = threadIdx.x;
    const int wv = t >> 6, L = t & 63;
    const int wr = (wv >> 1) * 32, wc = (wv & 1) * 32;
    const int l16 = L & 15, q = L >> 4;
    f32x4 acc[2][2];
#pragma unroll
    for (int i = 0; i < 2; ++i)
#pragma unroll
        for (int j = 0; j < 2; ++j)
            acc[i][j] = (f32x4){0.f, 0.f, 0.f, 0.f};

    if (t == 0) s_badcnt = 0;

    // Per-lane row pointers (K contiguous): A rows trow+wr+{0,16}+l16, B rows tcol+wc+{0,16}+l16.
    const ushort* Ar0 = A + (size_t)(trow + wr + l16) * CC + q * 8;
    const ushort* Ar1 = Ar0 + (size_t)16 * CC;
    const ushort* Br0 = B + (size_t)(tcol + wc + l16) * CC + q * 8;
    const ushort* Br1 = Br0 + (size_t)16 * CC;
#pragma unroll
    for (int kt = 0; kt < 8; ++kt) {
        const int kk = kt * 32;
        bf16x8 af0 = *(const bf16x8*)(Ar0 + kk);
        bf16x8 af1 = *(const bf16x8*)(Ar1 + kk);
        bf16x8 bf0 = *(const bf16x8*)(Br0 + kk);
        bf16x8 bf1 = *(const bf16x8*)(Br1 + kk);
        acc[0][0] = __builtin_amdgcn_mfma_f32_16x16x32_bf16(af0, bf0, acc[0][0], 0, 0, 0);
        acc[0][1] = __builtin_amdgcn_mfma_f32_16x16x32_bf16(af0, bf1, acc[0][1], 0, 0, 0);
        acc[1][0] = __builtin_amdgcn_mfma_f32_16x16x32_bf16(af1, bf0, acc[1][0], 0, 0, 0);
        acc[1][1] = __builtin_amdgcn_mfma_f32_16x16x32_bf16(af1, bf1, acc[1][1], 0, 0, 0);
    }

    // --- scan this block's 64 columns for flag!=1 entries (common case: none) ---
    if (t < 64) {
        const uint8_t* fb = flags + (((size_t)n * CC) + tcol + t) * 16;
        const uint4 fv = *(const uint4*)fb;
        if ((fv.x != 0x01010101u) || (fv.y != 0x01010101u) ||
            (fv.z != 0x01010101u) || (fv.w != 0x01010101u)) {
            for (int k = 0; k < 16; ++k) {
                const int f = fb[k];
                if (f != 1) {
                    int pos = atomicAdd(&s_badcnt, 1);
                    s_bad[pos] = (t << 8) | (k << 2) | f;
                }
            }
        }
    }
    __syncthreads();
    const int nbad = s_badcnt;
    for (int e = 0; e < nbad; ++e) {            // block-uniform cold path
        const int enc = s_bad[e];
        const int bl = enc >> 8, k = (enc >> 2) & 15, f = enc & 3;
        const int b = tcol + bl;
        {
            const float mv = adj[(size_t)n * 65536 + (size_t)t * CC + b];
            s_v[t] = (f == 0) ? fmaxf(mv, 0.f) : fmaxf(-mv, 0.f);
        }
        __syncthreads();
        {
            const float* cw = conv_w + (size_t)l * 1048576 +
                              (size_t)(trow + (t >> 2)) * 4096 + k * 256 + (t & 3) * 64;
            const float* vv = s_v + (t & 3) * 64;
            float s = 0.f;
#pragma unroll 16
            for (int a = 0; a < 64; ++a) s += cw[a] * vv[a];
            s += __shfl_xor(s, 1);
            s += __shfl_xor(s, 2);
            if ((t & 3) == 0) s_corr[t >> 2] = s;
        }
        __syncthreads();
#pragma unroll
        for (int j = 0; j < 2; ++j) {
            if (wc + j * 16 + l16 == bl) {
#pragma unroll
                for (int i = 0; i < 2; ++i)
#pragma unroll
                    for (int r = 0; r < 4; ++r)
                        acc[i][j][r] -= s_corr[wr + i * 16 + q * 4 + r];
            }
        }
        __syncthreads();
    }

    ushort* W = Ws + (size_t)ln * 65536;
#pragma unroll
    for (int i = 0; i < 2; ++i)
#pragma unroll
        for (int j = 0; j < 2; ++j) {
            const int ob = trow + wr + i * 16 + q * 4;       // D row = quad*4 + reg
            const int b  = tcol + wc + j * 16 + l16;         // D col = lane&15
#pragma unroll
            for (int r = 0; r < 4; ++r) {
                const int o = ob + r;
                const float sc = gamma[l * CC + o] * rsqrtf(var[l * CC + o] + EPSV);
                W[(size_t)o * CC + b] = f2bf(acc[i][j][r] * sc);
            }
        }
}

// ---------------------------------------------------------------------------
// Fused 3-layer chain. Block owns 16 p-rows x all 256 channels of one n.
// 512 threads (8 waves, 2 waves/SIMD) for 2x latency hiding on scattered W reads.
// Wave wv owns o-frags wv*2..wv*2+1. x panel in LDS ping-pong; W streamed from L2.
__global__ __launch_bounds__(512) void fused_layers(const float* __restrict__ feats,
                                                    const ushort* __restrict__ Ws,
                                                    const float* __restrict__ conv_b,
                                                    const float* __restrict__ gamma,
                                                    const float* __restrict__ beta,
                                                    const float* __restrict__ mean,
                                                    const float* __restrict__ var,
                                                    float* __restrict__ out) {
    const int n = blockIdx.y;
    const int p0 = blockIdx.x * 16;
    __shared__ ushort xl[2][16][264];   // +8 shorts pad
    const int t = threadIdx.x;
    const int wv = t >> 6, L = t & 63;
    const int l16 = L & 15, q = L >> 4;

    // Load + transpose x0: thread t = (channel c = t>>1, half = t&1), 8 p-values.
    {
        const int c = t >> 1, h = t & 1;
        const float* src = feats + ((size_t)n * CC + c) * HWP + p0 + h * 8;
        float v[8];
#pragma unroll
        for (int i = 0; i < 2; ++i)
            *(float4*)&v[i * 4] = *(const float4*)(src + i * 4);
#pragma unroll
        for (int i = 0; i < 8; ++i)
            xl[0][h * 8 + i][c] = f2bf(v[i]);
    }
    __syncthreads();

    int cur = 0;
    for (int l = 0; l < 3; ++l) {
        const ushort* Bw = Ws + (size_t)(l * 4 + n) * 65536;   // [o][b], b contig
        f32x4 acc[2];
#pragma unroll
        for (int jj = 0; jj < 2; ++jj) acc[jj] = (f32x4){0.f, 0.f, 0.f, 0.f};

#pragma unroll
        for (int kt = 0; kt < 8; ++kt) {
            const int kk = kt * 32;
            bf16x8 af = *(const bf16x8*)&xl[cur][l16][kk + q * 8];
#pragma unroll
            for (int jj = 0; jj < 2; ++jj) {
                const int o = (wv * 2 + jj) * 16 + l16;
                bf16x8 bv = *(const bf16x8*)(Bw + (size_t)o * CC + kk + q * 8);
                acc[jj] = __builtin_amdgcn_mfma_f32_16x16x32_bf16(af, bv, acc[jj], 0, 0, 0);
            }
        }

        float* outn = out + (size_t)(l * 4 + n) * CC * HWP;
#pragma unroll
        for (int jj = 0; jj < 2; ++jj) {
            const int o = (wv * 2 + jj) * 16 + l16;
            const float sc = gamma[l * CC + o] * rsqrtf(var[l * CC + o] + EPSV);
            const float b2 = sc * (conv_b[l * CC + o] - mean[l * CC + o]) + beta[l * CC + o];
            const float v0 = fmaxf(acc[jj][0] + b2, 0.f);
            const float v1 = fmaxf(acc[jj][1] + b2, 0.f);
            const float v2 = fmaxf(acc[jj][2] + b2, 0.f);
            const float v3 = fmaxf(acc[jj][3] + b2, 0.f);
            *(float4*)(outn + (size_t)o * HWP + p0 + q * 4) = (float4){v0, v1, v2, v3};
            if (l < 2) {
                xl[cur ^ 1][q * 4 + 0][o] = f2bf(v0);
                xl[cur ^ 1][q * 4 + 1][o] = f2bf(v1);
                xl[cur ^ 1][q * 4 + 2][o] = f2bf(v2);
                xl[cur ^ 1][q * 4 + 3][o] = f2bf(v3);
            }
        }
        __syncthreads();
        cur ^= 1;
    }
}

// ---------------------------------------------------------------------------
extern "C" void kernel_launch(void* const* d_in, const int* in_sizes, int n_in,
                              void* d_out, int out_size, void* d_ws, size_t ws_size,
                              hipStream_t stream) {
    const float* feats  = (const float*)d_in[0];
    const float* adj    = (const float*)d_in[1];
    const float* conv_w = (const float*)d_in[2];
    const float* conv_b = (const float*)d_in[3];
    const float* gamma  = (const float*)d_in[4];
    const float* beta   = (const float*)d_in[5];
    const float* mean   = (const float*)d_in[6];
    const float* var    = (const float*)d_in[7];
    float* out = (float*)d_out;

    // ws layout (bytes):
    //   [0, 16384)            flags uint8 [4][256][16]
    //   [16384, +393216)      cwS bf16 [3][256][256]
    //   [409600, +524288)     mpT bf16 [4][256][256]
    //   [933888, +1572864)    Ws  bf16 [12][256][256]
    char* ws = (char*)d_ws;
    uint8_t* flags = (uint8_t*)ws;
    ushort*  cwS   = (ushort*)(ws + 16384);
    ushort*  mpT   = (ushort*)(ws + 409600);
    ushort*  Wsb   = (ushort*)(ws + 933888);

    prep_kernel<<<256, 256, 0, stream>>>(adj, conv_w, mpT, flags, cwS);
    wbase_mfma<<<dim3(16, 12), 256, 0, stream>>>(cwS, mpT, flags, adj, conv_w, gamma, var, Wsb);
    fused_layers<<<dim3(64, NB), 512, 0, stream>>>(feats, Wsb, conv_b, gamma, beta, mean, var, out);
}